// Round 1
// baseline (46864.279 us; speedup 1.0000x reference)
//
#include <hip/hip_runtime.h>
#include <hip/hip_bf16.h>
#include <hip/hip_cooperative_groups.h>

namespace cg = cooperative_groups;

// Problem constants: T=512, B=64, D=1024, H=1024, 4H=4096
// Phase 1: G[t*64+b][0:4096] = x[t][b][:] @ Wi + bias   (big parallel GEMM)
// Phase 2: persistent cooperative kernel, 512 sequential steps:
//          z = G[t] + h_{t-1} @ Wh ; gates ; c,h update ; out[t] = h_t

// ---------------------------------------------------------------------------
// Phase 1: C[M=32768, N=4096] = A[M,1024] * W[1024,4096] + bias, f32 vector ALU
// 128x128 tile per WG, 256 threads, 8x8 per thread, BK=16.
// ---------------------------------------------------------------------------
template <typename GT>
__global__ __launch_bounds__(256)
void xwi_gemm(const float* __restrict__ A, const float* __restrict__ W,
              const float* __restrict__ bias, GT* __restrict__ G)
{
    __shared__ float As[16][132];   // [k][m], +4 pad
    __shared__ float Bs[16][132];   // [k][n], +4 pad
    const int bid = blockIdx.x;
    const int bm = bid >> 5;          // 256 M-tiles
    const int bn = bid & 31;          // 32  N-tiles
    const int t  = threadIdx.x;
    const int tx = t & 15, ty = t >> 4;
    const int m0 = bm * 128, n0 = bn * 128;

    float acc[8][8];
#pragma unroll
    for (int i = 0; i < 8; ++i)
#pragma unroll
        for (int j = 0; j < 8; ++j) acc[i][j] = 0.f;

    for (int kb = 0; kb < 1024; kb += 16) {
        // A tile: 128 rows x 16 k  -> As[k][m]
#pragma unroll
        for (int i = 0; i < 2; ++i) {
            int lin = t + i * 256;
            int r = lin >> 2, cq = (lin & 3) * 4;
            float4 v = *(const float4*)(A + (size_t)(m0 + r) * 1024 + kb + cq);
            As[cq + 0][r] = v.x; As[cq + 1][r] = v.y;
            As[cq + 2][r] = v.z; As[cq + 3][r] = v.w;
        }
        // W tile: 16 k x 128 cols -> Bs[k][n]
#pragma unroll
        for (int i = 0; i < 2; ++i) {
            int lin = t + i * 256;
            int kr = lin >> 5, nq = (lin & 31) * 4;
            float4 v = *(const float4*)(W + (size_t)(kb + kr) * 4096 + n0 + nq);
            *(float4*)&Bs[kr][nq] = v;
        }
        __syncthreads();
#pragma unroll
        for (int kk = 0; kk < 16; ++kk) {
            float4 a0 = *(const float4*)&As[kk][ty * 8];
            float4 a1 = *(const float4*)&As[kk][ty * 8 + 4];
            float4 b0 = *(const float4*)&Bs[kk][tx * 8];
            float4 b1 = *(const float4*)&Bs[kk][tx * 8 + 4];
            float av[8] = {a0.x, a0.y, a0.z, a0.w, a1.x, a1.y, a1.z, a1.w};
            float bv[8] = {b0.x, b0.y, b0.z, b0.w, b1.x, b1.y, b1.z, b1.w};
#pragma unroll
            for (int i = 0; i < 8; ++i)
#pragma unroll
                for (int j = 0; j < 8; ++j) acc[i][j] += av[i] * bv[j];
        }
        __syncthreads();
    }

    // epilogue: add bias, store
#pragma unroll
    for (int i = 0; i < 8; ++i) {
        size_t row = (size_t)(m0 + ty * 8 + i) * 4096 + n0 + tx * 8;
#pragma unroll
        for (int j = 0; j < 8; ++j) {
            float v = acc[i][j] + bias[n0 + tx * 8 + j];
            if constexpr (sizeof(GT) == 4) ((float*)G)[row + j] = v;
            else ((__hip_bfloat16*)G)[row + j] = __float2bfloat16(v);
        }
    }
}

// ---------------------------------------------------------------------------
// Phase 2: persistent cooperative LSTM scan.
// 256 WGs x 256 threads. WG wg owns hidden units j0..j0+3 (j0 = wg*4).
// Thread (b = t>>2, uu = t&3) owns cell (b, j0+uu): computes the 4 gate dots.
// Wh slice (16 cols x 1024 k = 64 KB) lives in LDS for the whole kernel,
// XOR-swizzled (word k ^ ((col&3)<<2)) so the 4 uu-lanes hit distinct banks.
// h double-buffered in ws; read straight from global (L2-resident, 256 KB).
// ---------------------------------------------------------------------------
template <typename GT>
__global__ __launch_bounds__(256)
void lstm_scan(const GT* __restrict__ G, const float* __restrict__ Wh,
               const float* __restrict__ h0, const float* __restrict__ c0,
               float* __restrict__ out, float* __restrict__ hb0,
               float* __restrict__ hb1)
{
    __shared__ float WhS[16][1024];   // exactly 64 KB static LDS
    const int wg = blockIdx.x;
    const int t  = threadIdx.x;
    const int b  = t >> 2, uu = t & 3;
    const int j0 = wg * 4;

    // Load this WG's 16 Wh columns into LDS (once), swizzled.
    for (int idx = t; idx < 16 * 1024; idx += 256) {
        int col = idx & 15, k = idx >> 4;
        int gc  = (col >> 2) * 1024 + j0 + (col & 3);  // gate*1024 + j
        WhS[col][k ^ ((col & 3) << 2)] = Wh[(size_t)k * 4096 + gc];
    }
    // Copy h0 -> hb0 (grid-strided).
    for (int idx = wg * 256 + t; idx < 64 * 1024; idx += 256 * 256)
        hb0[idx] = h0[idx];

    float c = c0[b * 1024 + j0 + uu];

    cg::grid_group grid = cg::this_grid();
    grid.sync();

    const int usw = uu << 2;
    for (int step = 0; step < 512; ++step) {
        const float* __restrict__ hp = (step & 1) ? hb1 : hb0;
        float* __restrict__ hn       = (step & 1) ? hb0 : hb1;
        const float* hrow = hp + b * 1024;

        float a0 = 0.f, a1 = 0.f, a2 = 0.f, a3 = 0.f;
#pragma unroll 4
        for (int kq = 0; kq < 1024; kq += 4) {
            float4 hv = *(const float4*)(hrow + kq);
            int ks = kq ^ usw;
            float4 w0 = *(const float4*)&WhS[uu][ks];
            float4 w1 = *(const float4*)&WhS[4 + uu][ks];
            float4 w2 = *(const float4*)&WhS[8 + uu][ks];
            float4 w3 = *(const float4*)&WhS[12 + uu][ks];
            a0 += hv.x * w0.x + hv.y * w0.y + hv.z * w0.z + hv.w * w0.w;
            a1 += hv.x * w1.x + hv.y * w1.y + hv.z * w1.z + hv.w * w1.w;
            a2 += hv.x * w2.x + hv.y * w2.y + hv.z * w2.z + hv.w * w2.w;
            a3 += hv.x * w3.x + hv.y * w3.y + hv.z * w3.z + hv.w * w3.w;
        }

        size_t gb = ((size_t)step * 64 + b) * 4096 + j0 + uu;
        float zi = (float)G[gb]        + a0;
        float zf = (float)G[gb + 1024] + a1;
        float zg = (float)G[gb + 2048] + a2;
        float zo = (float)G[gb + 3072] + a3;

        float ig = 1.f / (1.f + expf(-zi));
        float fg = 1.f / (1.f + expf(-zf));
        float gg = tanhf(zg);
        float og = 1.f / (1.f + expf(-zo));

        c = fg * c + ig * gg;
        float nh = og * tanhf(c);

        int hj = b * 1024 + j0 + uu;
        hn[hj] = nh;
        out[(size_t)step * (64 * 1024) + hj] = nh;

        __threadfence();
        grid.sync();
    }
}

// ---------------------------------------------------------------------------
extern "C" void kernel_launch(void* const* d_in, const int* in_sizes, int n_in,
                              void* d_out, int out_size, void* d_ws, size_t ws_size,
                              hipStream_t stream)
{
    const float* x  = (const float*)d_in[0];   // [512,64,1024]
    const float* h0 = (const float*)d_in[1];   // [64,1024]
    const float* c0 = (const float*)d_in[2];   // [64,1024]
    const float* Wi = (const float*)d_in[3];   // [1024,4096]
    const float* Wh = (const float*)d_in[4];   // [1024,4096]
    const float* bb = (const float*)d_in[5];   // [4096]
    float* out = (float*)d_out;                // [512,64,1024]

    float* hb0 = (float*)d_ws;
    float* hb1 = hb0 + 64 * 1024;
    char*  gbuf = (char*)d_ws + (size_t)2 * 64 * 1024 * 4;

    const size_t gelems = (size_t)512 * 64 * 4096;
    const size_t head   = (size_t)2 * 64 * 1024 * 4;
    bool use_f32 = (ws_size >= head + gelems * 4);

    if (use_f32) {
        float* G = (float*)gbuf;
        xwi_gemm<float><<<dim3(8192), dim3(256), 0, stream>>>(x, Wi, bb, G);
        void* args[] = {(void*)&G, (void*)&Wh, (void*)&h0, (void*)&c0,
                        (void*)&out, (void*)&hb0, (void*)&hb1};
        hipLaunchCooperativeKernel(reinterpret_cast<void*>(&lstm_scan<float>),
                                   dim3(256), dim3(256), args, 0, stream);
    } else {
        __hip_bfloat16* G = (__hip_bfloat16*)gbuf;
        xwi_gemm<__hip_bfloat16><<<dim3(8192), dim3(256), 0, stream>>>(x, Wi, bb, G);
        void* args[] = {(void*)&G, (void*)&Wh, (void*)&h0, (void*)&c0,
                        (void*)&out, (void*)&hb0, (void*)&hb1};
        hipLaunchCooperativeKernel(reinterpret_cast<void*>(&lstm_scan<__hip_bfloat16>),
                                   dim3(256), dim3(256), args, 0, stream);
    }
}

// Round 2
// 38903.091 us; speedup vs baseline: 1.2046x; 1.2046x over previous
//
#include <hip/hip_runtime.h>
#include <hip/hip_bf16.h>
#include <hip/hip_cooperative_groups.h>

namespace cg = cooperative_groups;

// T=512, B=64, D=1024, H=1024, 4H=4096
// Phase 1: G[t*64+b][:] = x[t][b][:] @ Wi + bias       (parallel GEMM, f32 VALU)
// Phase 2: cooperative scan; per step z = G[t] + h @ Wh via split-bf16 MFMA.

typedef __attribute__((ext_vector_type(8))) short bf16x8;
typedef __attribute__((ext_vector_type(4))) float f32x4;

static __device__ __forceinline__ unsigned short f2bf(float x) {
    __hip_bfloat16 h = __float2bfloat16(x);
    return __builtin_bit_cast(unsigned short, h);
}
static __device__ __forceinline__ float bf2f(unsigned short u) {
    __hip_bfloat16 h = __builtin_bit_cast(__hip_bfloat16, u);
    return __bfloat162float(h);
}

// ---------------------------------------------------------------------------
// Phase 1 (unchanged from verified round 1)
// ---------------------------------------------------------------------------
template <typename GT>
__global__ __launch_bounds__(256)
void xwi_gemm(const float* __restrict__ A, const float* __restrict__ W,
              const float* __restrict__ bias, GT* __restrict__ G)
{
    __shared__ float As[16][132];
    __shared__ float Bs[16][132];
    const int bid = blockIdx.x;
    const int bm = bid >> 5;
    const int bn = bid & 31;
    const int t  = threadIdx.x;
    const int tx = t & 15, ty = t >> 4;
    const int m0 = bm * 128, n0 = bn * 128;

    float acc[8][8];
#pragma unroll
    for (int i = 0; i < 8; ++i)
#pragma unroll
        for (int j = 0; j < 8; ++j) acc[i][j] = 0.f;

    for (int kb = 0; kb < 1024; kb += 16) {
#pragma unroll
        for (int i = 0; i < 2; ++i) {
            int lin = t + i * 256;
            int r = lin >> 2, cq = (lin & 3) * 4;
            float4 v = *(const float4*)(A + (size_t)(m0 + r) * 1024 + kb + cq);
            As[cq + 0][r] = v.x; As[cq + 1][r] = v.y;
            As[cq + 2][r] = v.z; As[cq + 3][r] = v.w;
        }
#pragma unroll
        for (int i = 0; i < 2; ++i) {
            int lin = t + i * 256;
            int kr = lin >> 5, nq = (lin & 31) * 4;
            float4 v = *(const float4*)(W + (size_t)(kb + kr) * 4096 + n0 + nq);
            *(float4*)&Bs[kr][nq] = v;
        }
        __syncthreads();
#pragma unroll
        for (int kk = 0; kk < 16; ++kk) {
            float4 a0 = *(const float4*)&As[kk][ty * 8];
            float4 a1 = *(const float4*)&As[kk][ty * 8 + 4];
            float4 b0 = *(const float4*)&Bs[kk][tx * 8];
            float4 b1 = *(const float4*)&Bs[kk][tx * 8 + 4];
            float av[8] = {a0.x, a0.y, a0.z, a0.w, a1.x, a1.y, a1.z, a1.w};
            float bv[8] = {b0.x, b0.y, b0.z, b0.w, b1.x, b1.y, b1.z, b1.w};
#pragma unroll
            for (int i = 0; i < 8; ++i)
#pragma unroll
                for (int j = 0; j < 8; ++j) acc[i][j] += av[i] * bv[j];
        }
        __syncthreads();
    }
#pragma unroll
    for (int i = 0; i < 8; ++i) {
        size_t row = (size_t)(m0 + ty * 8 + i) * 4096 + n0 + tx * 8;
#pragma unroll
        for (int j = 0; j < 8; ++j) {
            float v = acc[i][j] + bias[n0 + tx * 8 + j];
            if constexpr (sizeof(GT) == 4) ((float*)G)[row + j] = v;
            else ((__hip_bfloat16*)G)[row + j] = __float2bfloat16(v);
        }
    }
}

// ---------------------------------------------------------------------------
// Phase 2: cooperative MFMA scan.
// 256 WGs x 256 threads (4 waves). WG wg owns hidden units wg*4..wg*4+3 and
// z-columns {g*1024 + wg*4 + u}. Wave w computes z rows (batch) w*16..w*16+15
// for the 16 local cols, K=1024, split-bf16: hi*hi + lo*hi + hi*lo.
//
// Wh slice in LDS pre-packed in B-fragment order:
//   pos(k,c) = ((k>>5)*64 + ((k>>3)&3)*16 + c)*8 + (k&7)
// h broadcast in ws pre-packed in A-fragment order (hi/lo bf16):
//   p(k,b)   = ((k>>3)*64 + b)*8 + (k&7)
// Both operands use the same k-bijection, so the MFMA contraction is exact
// regardless of the hardware's internal k layout.
// ---------------------------------------------------------------------------
template <typename GT>
__global__ __launch_bounds__(256)
void lstm_scan_mfma(const GT* __restrict__ G, const float* __restrict__ Wh,
                    const float* __restrict__ h0, const float* __restrict__ c0,
                    float* __restrict__ out,
                    unsigned short* __restrict__ hpHi0, unsigned short* __restrict__ hpLo0,
                    unsigned short* __restrict__ hpHi1, unsigned short* __restrict__ hpLo1)
{
    __shared__ unsigned short WhHiS[32 * 64 * 8];   // 32 KB
    __shared__ unsigned short WhLoS[32 * 64 * 8];   // 32 KB
    __shared__ float zS[64 * 20];                   // transpose buffer (+pad)

    const int t  = threadIdx.x;
    const int wg = blockIdx.x;
    const int w  = t >> 6;
    const int l  = t & 63;
    const int lq = l >> 4, lc = l & 15;

    // Wh slice -> LDS, hi/lo split, fragment order. 64 elems/thread, once.
    for (int idx = t; idx < 16384; idx += 256) {
        int k = idx >> 4, c = idx & 15;
        int gcol = (c >> 2) * 1024 + wg * 4 + (c & 3);
        float wv = Wh[(size_t)k * 4096 + gcol];
        unsigned short hi = f2bf(wv);
        unsigned short lo = f2bf(wv - bf2f(hi));
        int pos = (((k >> 5) * 64) + (((k >> 3) & 3) * 16 + c)) * 8 + (k & 7);
        WhHiS[pos] = hi;
        WhLoS[pos] = lo;
    }

    // init hpack buffer 0 from h0 (grid-strided over 64*1024)
    for (int idx = wg * 256 + t; idx < 65536; idx += 256 * 256) {
        int b = idx >> 10, k = idx & 1023;
        float hv = h0[idx];
        unsigned short hi = f2bf(hv);
        unsigned short lo = f2bf(hv - bf2f(hi));
        int p = ((k >> 3) * 64 + b) * 8 + (k & 7);
        hpHi0[p] = hi;
        hpLo0[p] = lo;
    }

    const int b_el = t >> 2, u_el = t & 3;
    float c_state = c0[b_el * 1024 + wg * 4 + u_el];

    cg::grid_group grid = cg::this_grid();
    grid.sync();

    const int arow = w * 16 + lc;
    for (int step = 0; step < 512; ++step) {
        const unsigned short* __restrict__ hHi = (step & 1) ? hpHi1 : hpHi0;
        const unsigned short* __restrict__ hLo = (step & 1) ? hpLo1 : hpLo0;
        unsigned short* __restrict__ nHi = (step & 1) ? hpHi0 : hpHi1;
        unsigned short* __restrict__ nLo = (step & 1) ? hpLo0 : hpLo1;

        // prefetch G for this thread's elementwise (4 gates); latency hides
        // under the MFMA loop.
        float gv0, gv1, gv2, gv3;
        {
            size_t gb = ((size_t)step * 64 + b_el) * 4096 + wg * 4 + u_el;
            gv0 = (float)G[gb];
            gv1 = (float)G[gb + 1024];
            gv2 = (float)G[gb + 2048];
            gv3 = (float)G[gb + 3072];
        }

        f32x4 acc0 = {0.f, 0.f, 0.f, 0.f};
        f32x4 acc1 = {0.f, 0.f, 0.f, 0.f};
        f32x4 acc2 = {0.f, 0.f, 0.f, 0.f};
#pragma unroll 8
        for (int kb = 0; kb < 32; ++kb) {
            int apos = ((kb * 4 + lq) * 64 + arow) * 8;
            bf16x8 ah = *(const bf16x8*)(hHi + apos);
            bf16x8 al = *(const bf16x8*)(hLo + apos);
            int bpos = (kb * 64 + l) * 8;
            bf16x8 bh = *(const bf16x8*)(WhHiS + bpos);
            bf16x8 bl = *(const bf16x8*)(WhLoS + bpos);
            acc0 = __builtin_amdgcn_mfma_f32_16x16x32_bf16(ah, bh, acc0, 0, 0, 0);
            acc1 = __builtin_amdgcn_mfma_f32_16x16x32_bf16(al, bh, acc1, 0, 0, 0);
            acc2 = __builtin_amdgcn_mfma_f32_16x16x32_bf16(ah, bl, acc2, 0, 0, 0);
        }

        // z tile -> LDS (row = w*16 + lq*4 + r, col = lc), stride 20 pads banks
#pragma unroll
        for (int r = 0; r < 4; ++r)
            zS[(w * 16 + lq * 4 + r) * 20 + lc] = acc0[r] + acc1[r] + acc2[r];
        __syncthreads();

        // elementwise: thread owns (b_el, unit u_el)
        float zi = gv0 + zS[b_el * 20 + u_el];
        float zf = gv1 + zS[b_el * 20 + 4 + u_el];
        float zg = gv2 + zS[b_el * 20 + 8 + u_el];
        float zo = gv3 + zS[b_el * 20 + 12 + u_el];

        float ig = 1.f / (1.f + __expf(-zi));
        float fg = 1.f / (1.f + __expf(-zf));
        float gg = tanhf(zg);
        float og = 1.f / (1.f + __expf(-zo));

        c_state = fg * c_state + ig * gg;
        float nh = og * tanhf(c_state);

        int j = wg * 4 + u_el;
        out[(size_t)step * 65536 + b_el * 1024 + j] = nh;
        unsigned short hi = f2bf(nh);
        unsigned short lo = f2bf(nh - bf2f(hi));
        int p = ((j >> 3) * 64 + b_el) * 8 + (j & 7);
        nHi[p] = hi;
        nLo[p] = lo;

        __threadfence();
        grid.sync();
    }
}

// ---------------------------------------------------------------------------
extern "C" void kernel_launch(void* const* d_in, const int* in_sizes, int n_in,
                              void* d_out, int out_size, void* d_ws, size_t ws_size,
                              hipStream_t stream)
{
    const float* x  = (const float*)d_in[0];
    const float* h0 = (const float*)d_in[1];
    const float* c0 = (const float*)d_in[2];
    const float* Wi = (const float*)d_in[3];
    const float* Wh = (const float*)d_in[4];
    const float* bb = (const float*)d_in[5];
    float* out = (float*)d_out;

    // ws layout: 4 hpack buffers (128 KB each) then G
    unsigned short* hpHi0 = (unsigned short*)d_ws;
    unsigned short* hpLo0 = hpHi0 + 65536;
    unsigned short* hpHi1 = hpLo0 + 65536;
    unsigned short* hpLo1 = hpHi1 + 65536;
    char* gbuf = (char*)d_ws + (size_t)4 * 65536 * 2;

    const size_t gelems = (size_t)512 * 64 * 4096;
    const size_t head   = (size_t)4 * 65536 * 2;
    bool use_f32 = (ws_size >= head + gelems * 4);

    if (use_f32) {
        float* G = (float*)gbuf;
        xwi_gemm<float><<<dim3(8192), dim3(256), 0, stream>>>(x, Wi, bb, G);
        void* args[] = {(void*)&G, (void*)&Wh, (void*)&h0, (void*)&c0, (void*)&out,
                        (void*)&hpHi0, (void*)&hpLo0, (void*)&hpHi1, (void*)&hpLo1};
        hipLaunchCooperativeKernel(reinterpret_cast<void*>(&lstm_scan_mfma<float>),
                                   dim3(256), dim3(256), args, 0, stream);
    } else {
        __hip_bfloat16* G = (__hip_bfloat16*)gbuf;
        xwi_gemm<__hip_bfloat16><<<dim3(8192), dim3(256), 0, stream>>>(x, Wi, bb, G);
        void* args[] = {(void*)&G, (void*)&Wh, (void*)&h0, (void*)&c0, (void*)&out,
                        (void*)&hpHi0, (void*)&hpLo0, (void*)&hpHi1, (void*)&hpLo1};
        hipLaunchCooperativeKernel(reinterpret_cast<void*>(&lstm_scan_mfma<__hip_bfloat16>),
                                   dim3(256), dim3(256), args, 0, stream);
    }
}

// Round 3
// 7999.760 us; speedup vs baseline: 5.8582x; 4.8630x over previous
//
#include <hip/hip_runtime.h>
#include <hip/hip_bf16.h>
#include <hip/hip_cooperative_groups.h>

// T=512, B=64, D=1024, H=1024, 4H=4096
// Phase 1: G[t*64+b][:] = x[t][b][:] @ Wi + bias       (parallel GEMM, f32 VALU)
// Phase 2: cooperative scan; per step z = G[t] + h @ Wh via split-bf16 MFMA.
//          Custom flag-array barrier (relaxed agent atomics, sc1 write-through)
//          replaces cg::grid.sync() — round 2 showed grid.sync ~68 us/step.

typedef __attribute__((ext_vector_type(8))) short bf16x8;
typedef __attribute__((ext_vector_type(4))) float f32x4;
typedef __attribute__((ext_vector_type(2))) unsigned long long u64x2;

static __device__ __forceinline__ unsigned short f2bf(float x) {
    __hip_bfloat16 h = __float2bfloat16(x);
    return __builtin_bit_cast(unsigned short, h);
}
static __device__ __forceinline__ float bf2f(unsigned short u) {
    __hip_bfloat16 h = __builtin_bit_cast(__hip_bfloat16, u);
    return __bfloat162float(h);
}

// coherent (agent-scope, L2-bypassing) 16B h-fragment load as 2 x u64 atomics
static __device__ __forceinline__ bf16x8 ld_h16(const unsigned long long* p) {
    unsigned long long a = __hip_atomic_load(p,     __ATOMIC_RELAXED, __HIP_MEMORY_SCOPE_AGENT);
    unsigned long long b = __hip_atomic_load(p + 1, __ATOMIC_RELAXED, __HIP_MEMORY_SCOPE_AGENT);
    u64x2 v; v.x = a; v.y = b;
    return __builtin_bit_cast(bf16x8, v);
}

// ---------------------------------------------------------------------------
// Phase 1 (unchanged, verified)
// ---------------------------------------------------------------------------
template <typename GT>
__global__ __launch_bounds__(256)
void xwi_gemm(const float* __restrict__ A, const float* __restrict__ W,
              const float* __restrict__ bias, GT* __restrict__ G)
{
    __shared__ float As[16][132];
    __shared__ float Bs[16][132];
    const int bid = blockIdx.x;
    const int bm = bid >> 5;
    const int bn = bid & 31;
    const int t  = threadIdx.x;
    const int tx = t & 15, ty = t >> 4;
    const int m0 = bm * 128, n0 = bn * 128;

    float acc[8][8];
#pragma unroll
    for (int i = 0; i < 8; ++i)
#pragma unroll
        for (int j = 0; j < 8; ++j) acc[i][j] = 0.f;

    for (int kb = 0; kb < 1024; kb += 16) {
#pragma unroll
        for (int i = 0; i < 2; ++i) {
            int lin = t + i * 256;
            int r = lin >> 2, cq = (lin & 3) * 4;
            float4 v = *(const float4*)(A + (size_t)(m0 + r) * 1024 + kb + cq);
            As[cq + 0][r] = v.x; As[cq + 1][r] = v.y;
            As[cq + 2][r] = v.z; As[cq + 3][r] = v.w;
        }
#pragma unroll
        for (int i = 0; i < 2; ++i) {
            int lin = t + i * 256;
            int kr = lin >> 5, nq = (lin & 31) * 4;
            float4 v = *(const float4*)(W + (size_t)(kb + kr) * 4096 + n0 + nq);
            *(float4*)&Bs[kr][nq] = v;
        }
        __syncthreads();
#pragma unroll
        for (int kk = 0; kk < 16; ++kk) {
            float4 a0 = *(const float4*)&As[kk][ty * 8];
            float4 a1 = *(const float4*)&As[kk][ty * 8 + 4];
            float4 b0 = *(const float4*)&Bs[kk][tx * 8];
            float4 b1 = *(const float4*)&Bs[kk][tx * 8 + 4];
            float av[8] = {a0.x, a0.y, a0.z, a0.w, a1.x, a1.y, a1.z, a1.w};
            float bv[8] = {b0.x, b0.y, b0.z, b0.w, b1.x, b1.y, b1.z, b1.w};
#pragma unroll
            for (int i = 0; i < 8; ++i)
#pragma unroll
                for (int j = 0; j < 8; ++j) acc[i][j] += av[i] * bv[j];
        }
        __syncthreads();
    }
#pragma unroll
    for (int i = 0; i < 8; ++i) {
        size_t row = (size_t)(m0 + ty * 8 + i) * 4096 + n0 + tx * 8;
#pragma unroll
        for (int j = 0; j < 8; ++j) {
            float v = acc[i][j] + bias[n0 + tx * 8 + j];
            if constexpr (sizeof(GT) == 4) ((float*)G)[row + j] = v;
            else ((__hip_bfloat16*)G)[row + j] = __float2bfloat16(v);
        }
    }
}

// ---------------------------------------------------------------------------
// Decentralized barrier: WG wg stores target to flags[wg*32]; thread t polls
// flags[t*32]. All cross-WG data was written with sc1 (agent) stores, so
// s_waitcnt vmcnt(0) before the flag store is the release; sc1 polls/loads
// are the acquire. No L2 flush/invalidate anywhere.
// ---------------------------------------------------------------------------
static __device__ __forceinline__ void gbar(unsigned int* flags, int wg, int t,
                                            unsigned int target) {
    asm volatile("s_waitcnt vmcnt(0)" ::: "memory");
    __syncthreads();
    if (t == 0)
        __hip_atomic_store(&flags[wg * 32], target, __ATOMIC_RELAXED,
                           __HIP_MEMORY_SCOPE_AGENT);
    while (__hip_atomic_load(&flags[t * 32], __ATOMIC_RELAXED,
                             __HIP_MEMORY_SCOPE_AGENT) < target) {}
    __syncthreads();
    asm volatile("" ::: "memory");
}

// ---------------------------------------------------------------------------
// Phase 2: cooperative MFMA scan, custom barrier.
// 256 WGs x 256 threads (4 waves). WG wg owns hidden units wg*4..wg*4+3.
// Wh slice in LDS (B-fragment order, hi/lo split bf16). h broadcast via ws
// in A-fragment order (hi/lo), published with agent-scope atomic stores.
// ---------------------------------------------------------------------------
template <typename GT>
__global__ __launch_bounds__(256)
void lstm_scan_mfma(const GT* __restrict__ G, const float* __restrict__ Wh,
                    const float* __restrict__ h0, const float* __restrict__ c0,
                    float* __restrict__ out,
                    unsigned int* __restrict__ hp0, unsigned int* __restrict__ lp0,
                    unsigned int* __restrict__ hp1, unsigned int* __restrict__ lp1,
                    unsigned int* __restrict__ flags)
{
    __shared__ unsigned short WhHiS[32 * 64 * 8];   // 32 KB
    __shared__ unsigned short WhLoS[32 * 64 * 8];   // 32 KB
    __shared__ float zS[64 * 20];

    const int t  = threadIdx.x;
    const int wg = blockIdx.x;
    const int w  = t >> 6;
    const int l  = t & 63;
    const int lq = l >> 4, lc = l & 15;

    // Wh slice -> LDS (once)
    for (int idx = t; idx < 16384; idx += 256) {
        int k = idx >> 4, c = idx & 15;
        int gcol = (c >> 2) * 1024 + wg * 4 + (c & 3);
        float wv = Wh[(size_t)k * 4096 + gcol];
        unsigned short hi = f2bf(wv);
        unsigned short lo = f2bf(wv - bf2f(hi));
        int pos = (((k >> 5) * 64) + (((k >> 3) & 3) * 16 + c)) * 8 + (k & 7);
        WhHiS[pos] = hi;
        WhLoS[pos] = lo;
    }

    // init hpack buffer 0 from h0: one k-pair per thread (32768 pairs)
    {
        int idx = wg * 256 + t;
        if (idx < 32768) {
            int b = idx >> 9;
            int k = (idx & 511) * 2;
            float v0 = h0[b * 1024 + k];
            float v1 = h0[b * 1024 + k + 1];
            unsigned short h0s = f2bf(v0), h1s = f2bf(v1);
            unsigned short l0s = f2bf(v0 - bf2f(h0s)), l1s = f2bf(v1 - bf2f(h1s));
            int p32 = ((k >> 3) * 64 + b) * 4 + ((k & 7) >> 1);
            __hip_atomic_store(hp0 + p32, (unsigned int)h0s | ((unsigned int)h1s << 16),
                               __ATOMIC_RELAXED, __HIP_MEMORY_SCOPE_AGENT);
            __hip_atomic_store(lp0 + p32, (unsigned int)l0s | ((unsigned int)l1s << 16),
                               __ATOMIC_RELAXED, __HIP_MEMORY_SCOPE_AGENT);
        }
    }

    const int b_el = t >> 2, u_el = t & 3;
    float c_state = c0[b_el * 1024 + wg * 4 + u_el];

    gbar(flags, wg, t, 1u);

    const int arow = w * 16 + lc;
    for (int step = 0; step < 512; ++step) {
        const unsigned long long* hH =
            (const unsigned long long*)((step & 1) ? hp1 : hp0);
        const unsigned long long* hL =
            (const unsigned long long*)((step & 1) ? lp1 : lp0);
        unsigned int* nH = (step & 1) ? hp0 : hp1;
        unsigned int* nL = (step & 1) ? lp0 : lp1;

        // prefetch G (latency hides under MFMA loop)
        float gv0, gv1, gv2, gv3;
        {
            size_t gb = ((size_t)step * 64 + b_el) * 4096 + wg * 4 + u_el;
            gv0 = (float)G[gb];
            gv1 = (float)G[gb + 1024];
            gv2 = (float)G[gb + 2048];
            gv3 = (float)G[gb + 3072];
        }

        f32x4 acc0 = {0.f, 0.f, 0.f, 0.f};
        f32x4 acc1 = {0.f, 0.f, 0.f, 0.f};
        f32x4 acc2 = {0.f, 0.f, 0.f, 0.f};
#pragma unroll 8
        for (int kb = 0; kb < 32; ++kb) {
            int a64 = ((kb * 4 + lq) * 64 + arow) * 2;  // u64 index
            bf16x8 ah = ld_h16(hH + a64);
            bf16x8 al = ld_h16(hL + a64);
            int bpos = (kb * 64 + l) * 8;
            bf16x8 bh = *(const bf16x8*)(WhHiS + bpos);
            bf16x8 bl = *(const bf16x8*)(WhLoS + bpos);
            acc0 = __builtin_amdgcn_mfma_f32_16x16x32_bf16(ah, bh, acc0, 0, 0, 0);
            acc1 = __builtin_amdgcn_mfma_f32_16x16x32_bf16(al, bh, acc1, 0, 0, 0);
            acc2 = __builtin_amdgcn_mfma_f32_16x16x32_bf16(ah, bl, acc2, 0, 0, 0);
        }

        // z tile -> LDS transpose
#pragma unroll
        for (int r = 0; r < 4; ++r)
            zS[(w * 16 + lq * 4 + r) * 20 + lc] = acc0[r] + acc1[r] + acc2[r];
        __syncthreads();

        float zi = gv0 + zS[b_el * 20 + u_el];
        float zf = gv1 + zS[b_el * 20 + 4 + u_el];
        float zg = gv2 + zS[b_el * 20 + 8 + u_el];
        float zo = gv3 + zS[b_el * 20 + 12 + u_el];

        float ig = 1.f / (1.f + __expf(-zi));
        float fg = 1.f / (1.f + __expf(-zf));
        float gg = tanhf(zg);
        float og = 1.f / (1.f + __expf(-zo));

        c_state = fg * c_state + ig * gg;
        float nh = og * tanhf(c_state);

        int j = wg * 4 + u_el;
        out[(size_t)step * 65536 + b_el * 1024 + j] = nh;

        // publish h: pack (j even, j odd) pairs into u32, agent-scope stores
        unsigned int hiw = f2bf(nh);
        unsigned int low = f2bf(nh - bf2f((unsigned short)hiw));
        unsigned int hi_o = (unsigned int)__shfl_xor((int)hiw, 1);
        unsigned int lo_o = (unsigned int)__shfl_xor((int)low, 1);
        if ((t & 1) == 0) {
            int p32 = ((j >> 3) * 64 + b_el) * 4 + ((j & 7) >> 1);
            __hip_atomic_store(nH + p32, (hiw & 0xffffu) | (hi_o << 16),
                               __ATOMIC_RELAXED, __HIP_MEMORY_SCOPE_AGENT);
            __hip_atomic_store(nL + p32, (low & 0xffffu) | (lo_o << 16),
                               __ATOMIC_RELAXED, __HIP_MEMORY_SCOPE_AGENT);
        }

        gbar(flags, wg, t, (unsigned int)(step + 2));
    }
}

// ---------------------------------------------------------------------------
extern "C" void kernel_launch(void* const* d_in, const int* in_sizes, int n_in,
                              void* d_out, int out_size, void* d_ws, size_t ws_size,
                              hipStream_t stream)
{
    const float* x  = (const float*)d_in[0];
    const float* h0 = (const float*)d_in[1];
    const float* c0 = (const float*)d_in[2];
    const float* Wi = (const float*)d_in[3];
    const float* Wh = (const float*)d_in[4];
    const float* bb = (const float*)d_in[5];
    float* out = (float*)d_out;

    // ws layout: 4 hpack buffers (128 KB each), flags (32 KB), then G
    unsigned int* hp0 = (unsigned int*)d_ws;
    unsigned int* lp0 = hp0 + 32768;
    unsigned int* hp1 = lp0 + 32768;
    unsigned int* lp1 = hp1 + 32768;
    unsigned int* flags = lp1 + 32768;          // 256 * 32 u32 = 32 KB
    char* gbuf = (char*)d_ws + 4 * 131072 + 32768;

    const size_t gelems = (size_t)512 * 64 * 4096;
    const size_t head   = 4 * 131072 + 32768;
    bool use_f32 = (ws_size >= head + gelems * 4);

    hipMemsetAsync(flags, 0, 256 * 32 * sizeof(unsigned int), stream);

    if (use_f32) {
        float* G = (float*)gbuf;
        xwi_gemm<float><<<dim3(8192), dim3(256), 0, stream>>>(x, Wi, bb, G);
        void* args[] = {(void*)&G, (void*)&Wh, (void*)&h0, (void*)&c0, (void*)&out,
                        (void*)&hp0, (void*)&lp0, (void*)&hp1, (void*)&lp1,
                        (void*)&flags};
        hipLaunchCooperativeKernel(reinterpret_cast<void*>(&lstm_scan_mfma<float>),
                                   dim3(256), dim3(256), args, 0, stream);
    } else {
        __hip_bfloat16* G = (__hip_bfloat16*)gbuf;
        xwi_gemm<__hip_bfloat16><<<dim3(8192), dim3(256), 0, stream>>>(x, Wi, bb, G);
        void* args[] = {(void*)&G, (void*)&Wh, (void*)&h0, (void*)&c0, (void*)&out,
                        (void*)&hp0, (void*)&lp0, (void*)&hp1, (void*)&lp1,
                        (void*)&flags};
        hipLaunchCooperativeKernel(reinterpret_cast<void*>(&lstm_scan_mfma<__hip_bfloat16>),
                                   dim3(256), dim3(256), args, 0, stream);
    }
}

// Round 4
// 7619.109 us; speedup vs baseline: 6.1509x; 1.0500x over previous
//
#include <hip/hip_runtime.h>
#include <hip/hip_bf16.h>

// T=512, B=64, D=1024, H=1024, 4H=4096
// Pass 0: pack Wi -> split-bf16 (hi/lo) in MFMA B-fragment order (ws, 16MB)
// Pass 1: G[t*64+b][:] = x @ Wi + b  via split-bf16 MFMA, G stored bf16 (ws)
// Pass 2: cooperative scan, 128 WGs x 8 hidden units, split-bf16 MFMA,
//         flag-array barrier + sc1 h broadcast (32 MB/step chip-wide).

typedef __attribute__((ext_vector_type(8))) short bf16x8;
typedef __attribute__((ext_vector_type(8))) unsigned short ushx8;
typedef __attribute__((ext_vector_type(4))) unsigned short ushx4;
typedef __attribute__((ext_vector_type(4))) float f32x4;
typedef __attribute__((ext_vector_type(2))) unsigned long long u64x2;

static __device__ __forceinline__ unsigned short f2bf(float x) {
    __hip_bfloat16 h = __float2bfloat16(x);
    return __builtin_bit_cast(unsigned short, h);
}
static __device__ __forceinline__ float bf2f(unsigned short u) {
    __hip_bfloat16 h = __builtin_bit_cast(__hip_bfloat16, u);
    return __bfloat162float(h);
}

// coherent (agent-scope, L2-bypassing) 16B load as 2 x u64 relaxed atomics
static __device__ __forceinline__ bf16x8 ld_h16(const unsigned long long* p) {
    unsigned long long a = __hip_atomic_load(p,     __ATOMIC_RELAXED, __HIP_MEMORY_SCOPE_AGENT);
    unsigned long long b = __hip_atomic_load(p + 1, __ATOMIC_RELAXED, __HIP_MEMORY_SCOPE_AGENT);
    u64x2 v; v.x = a; v.y = b;
    return __builtin_bit_cast(bf16x8, v);
}

static __device__ __forceinline__ void gl_lds16(const void* g, void* l) {
    __builtin_amdgcn_global_load_lds(
        (const __attribute__((address_space(1))) unsigned int*)g,
        (__attribute__((address_space(3))) unsigned int*)l, 16, 0, 0);
}

// ---------------------------------------------------------------------------
// Pass 0: pack Wi[1024][4096] f32 -> WiHi/WiLo bf16 in B-fragment order.
// Layout: slab (tn, kb) of 4096 shorts: idx = kq*1024 + c*8 + (k&7),
//         kq = (k&31)>>3, c = col within 128-tile. Slab = 8KB = LDS image.
// ---------------------------------------------------------------------------
__global__ __launch_bounds__(256)
void wi_pack(const float* __restrict__ Wi, unsigned short* __restrict__ WiHi,
             unsigned short* __restrict__ WiLo)
{
    const int bid = blockIdx.x;            // 1024 = tn(32) x kb(32)
    const int tn = bid >> 5, kb = bid & 31;
    const int t = threadIdx.x;
    const int c = t & 127, ko = t >> 7;    // ko: which 16-k half
    const float* src = Wi + (size_t)(kb * 32 + ko * 16) * 4096 + tn * 128 + c;
    const size_t dbase = ((size_t)(tn * 32 + kb)) * 4096 + c * 8;
#pragma unroll
    for (int o = 0; o < 2; ++o) {
        ushx8 hv, lv;
#pragma unroll
        for (int q = 0; q < 8; ++q) {
            float v = src[(size_t)(o * 8 + q) * 4096];
            unsigned short h = f2bf(v);
            hv[q] = h; lv[q] = f2bf(v - bf2f(h));
        }
        int kq = ko * 2 + o;
        *(ushx8*)(WiHi + dbase + kq * 1024) = hv;
        *(ushx8*)(WiLo + dbase + kq * 1024) = lv;
    }
}

// ---------------------------------------------------------------------------
// Pass 1: G = x @ Wi + bias, split-bf16 MFMA, 128x128 tile, BK=32, 4 waves.
// First MFMA operand = Wi-frag (M-dim = n), second = x-frag (N-dim = m):
// lane then holds 4 consecutive n per reg -> 8B bf16 stores.
// ---------------------------------------------------------------------------
__global__ __launch_bounds__(256)
void xwi_gemm_mfma(const float* __restrict__ x,
                   const unsigned short* __restrict__ WiHi,
                   const unsigned short* __restrict__ WiLo,
                   const float* __restrict__ bias,
                   __hip_bfloat16* __restrict__ G)
{
    __shared__ __align__(16) unsigned short AHi[4096], ALo[4096];
    __shared__ __align__(16) unsigned short BHi[4096], BLo[4096];
    const int bid = blockIdx.x;
    const int bm = bid >> 5, bn = bid & 31;
    const int m0 = bm << 7, n0 = bn << 7;
    const int t = threadIdx.x;
    const int w = t >> 6, l = t & 63, lq = l >> 4, lc = l & 15;
    const int wm = w >> 1, wn = w & 1;

    f32x4 acc[4][4] = {};
    const int row = t >> 1, kh = t & 1;
    const float* xrow = x + (size_t)(m0 + row) * 1024 + kh * 16;
    const unsigned short* bHsl = WiHi + (size_t)(bn * 32) * 4096;
    const unsigned short* bLsl = WiLo + (size_t)(bn * 32) * 4096;

    for (int kb = 0; kb < 32; ++kb) {
        // A stage: 16 f32 -> hi/lo bf16 octets
        float4 f0 = *(const float4*)(xrow + kb * 32 + 0);
        float4 f1 = *(const float4*)(xrow + kb * 32 + 4);
        float4 f2 = *(const float4*)(xrow + kb * 32 + 8);
        float4 f3 = *(const float4*)(xrow + kb * 32 + 12);
        float fs[16] = {f0.x, f0.y, f0.z, f0.w, f1.x, f1.y, f1.z, f1.w,
                        f2.x, f2.y, f2.z, f2.w, f3.x, f3.y, f3.z, f3.w};
#pragma unroll
        for (int o = 0; o < 2; ++o) {
            ushx8 hv, lv;
#pragma unroll
            for (int q = 0; q < 8; ++q) {
                float v = fs[o * 8 + q];
                unsigned short h = f2bf(v);
                hv[q] = h; lv[q] = f2bf(v - bf2f(h));
            }
            int kq = kh * 2 + o;
            *(ushx8*)&AHi[kq * 1024 + row * 8] = hv;
            *(ushx8*)&ALo[kq * 1024 + row * 8] = lv;
        }
        // B stage: linear 8KB slab copies via global_load_lds (16B/lane)
        {
            const unsigned short* sH = bHsl + (size_t)kb * 4096;
            const unsigned short* sL = bLsl + (size_t)kb * 4096;
            gl_lds16(sH + (size_t)(w * 128 + l) * 8,      &BHi[(w * 128) * 8]);
            gl_lds16(sH + (size_t)(w * 128 + 64 + l) * 8, &BHi[(w * 128 + 64) * 8]);
            gl_lds16(sL + (size_t)(w * 128 + l) * 8,      &BLo[(w * 128) * 8]);
            gl_lds16(sL + (size_t)(w * 128 + 64 + l) * 8, &BLo[(w * 128 + 64) * 8]);
        }
        __syncthreads();

        bf16x8 xh[4], xl[4], wh_[4], wl_[4];
#pragma unroll
        for (int a = 0; a < 4; ++a) {
            int off = lq * 1024 + (wm * 64 + a * 16 + lc) * 8;
            xh[a] = *(const bf16x8*)&AHi[off];
            xl[a] = *(const bf16x8*)&ALo[off];
        }
#pragma unroll
        for (int b = 0; b < 4; ++b) {
            int off = lq * 1024 + (wn * 64 + b * 16 + lc) * 8;
            wh_[b] = *(const bf16x8*)&BHi[off];
            wl_[b] = *(const bf16x8*)&BLo[off];
        }
#pragma unroll
        for (int a = 0; a < 4; ++a)
#pragma unroll
            for (int b = 0; b < 4; ++b) {
                acc[a][b] = __builtin_amdgcn_mfma_f32_16x16x32_bf16(wh_[b], xh[a], acc[a][b], 0, 0, 0);
                acc[a][b] = __builtin_amdgcn_mfma_f32_16x16x32_bf16(wl_[b], xh[a], acc[a][b], 0, 0, 0);
                acc[a][b] = __builtin_amdgcn_mfma_f32_16x16x32_bf16(wh_[b], xl[a], acc[a][b], 0, 0, 0);
            }
        __syncthreads();
    }

    // epilogue: + bias, store bf16 (4 consecutive n per 8B store)
    float bv[4][4];
#pragma unroll
    for (int b = 0; b < 4; ++b)
#pragma unroll
        for (int r = 0; r < 4; ++r)
            bv[b][r] = bias[n0 + wn * 64 + b * 16 + lq * 4 + r];
#pragma unroll
    for (int a = 0; a < 4; ++a) {
        int m = m0 + wm * 64 + a * 16 + lc;
        __hip_bfloat16* Gr = G + (size_t)m * 4096 + n0 + wn * 64 + lq * 4;
#pragma unroll
        for (int b = 0; b < 4; ++b) {
            ushx4 sv;
#pragma unroll
            for (int r = 0; r < 4; ++r) sv[r] = f2bf(acc[a][b][r] + bv[b][r]);
            *(ushx4*)(Gr + b * 16) = sv;
        }
    }
}

// ---------------------------------------------------------------------------
// Decentralized barrier (128 WGs): WG wg stores target to flags[wg*32];
// threads t<128 poll flags[t*32]. sc1 stores drained by vmcnt(0) = release.
// ---------------------------------------------------------------------------
static __device__ __forceinline__ void gbar(unsigned int* flags, int wg, int t,
                                            unsigned int target) {
    asm volatile("s_waitcnt vmcnt(0)" ::: "memory");
    __syncthreads();
    if (t == 0)
        __hip_atomic_store(&flags[wg * 32], target, __ATOMIC_RELAXED,
                           __HIP_MEMORY_SCOPE_AGENT);
    if (t < 128)
        while (__hip_atomic_load(&flags[t * 32], __ATOMIC_RELAXED,
                                 __HIP_MEMORY_SCOPE_AGENT) < target) {}
    __syncthreads();
    asm volatile("" ::: "memory");
}

// ---------------------------------------------------------------------------
// Pass 2: cooperative MFMA scan. 128 WGs x 256 threads (4 waves).
// WG owns 8 hidden units (32 z-cols = 2 MFMA col-tiles), Wh slice 128KB LDS.
// Wave w computes batch rows w*16..+15. A-frags (h) reused across both
// col-tiles -> chip h traffic 32 MB/step.
// ---------------------------------------------------------------------------
__global__ __launch_bounds__(256)
void lstm_scan_mfma(const __hip_bfloat16* __restrict__ G,
                    const float* __restrict__ Wh,
                    const float* __restrict__ h0, const float* __restrict__ c0,
                    float* __restrict__ out,
                    unsigned int* __restrict__ hp0, unsigned int* __restrict__ lp0,
                    unsigned int* __restrict__ hp1, unsigned int* __restrict__ lp1,
                    unsigned int* __restrict__ flags)
{
    __shared__ __align__(16) unsigned short WhHiS[32768];  // 64 KB, [ct][frag]
    __shared__ __align__(16) unsigned short WhLoS[32768];  // 64 KB
    __shared__ float zS[64 * 33];                          // 8.4 KB

    const int t  = threadIdx.x;
    const int wg = blockIdx.x;           // 0..127
    const int w  = t >> 6;
    const int l  = t & 63;
    const int lq = l >> 4, lc = l & 15;

    // Wh slice -> LDS (once): 32 z-cols (gate*8+unit), hi/lo split, frag order
    for (int idx = t; idx < 32768; idx += 256) {
        int k = idx >> 5, c5 = idx & 31;
        int gcol = (c5 >> 3) * 1024 + wg * 8 + (c5 & 7);
        float wv = Wh[(size_t)k * 4096 + gcol];
        unsigned short hi = f2bf(wv);
        unsigned short lo = f2bf(wv - bf2f(hi));
        int ct = c5 >> 4, c = c5 & 15;
        int pos = ct * 16384 + (((k >> 5) * 64) + (((k >> 3) & 3) * 16 + c)) * 8 + (k & 7);
        WhHiS[pos] = hi; WhLoS[pos] = lo;
    }

    // init hpack buffer 0 from h0: exactly one k-pair per thread (32768)
    {
        int idx = wg * 256 + t;
        int b = idx >> 9, k = (idx & 511) * 2;
        float v0 = h0[b * 1024 + k], v1 = h0[b * 1024 + k + 1];
        unsigned short h0s = f2bf(v0), h1s = f2bf(v1);
        unsigned short l0s = f2bf(v0 - bf2f(h0s)), l1s = f2bf(v1 - bf2f(h1s));
        int p32 = ((k >> 3) * 64 + b) * 4 + ((k & 7) >> 1);
        __hip_atomic_store(hp0 + p32, (unsigned int)h0s | ((unsigned int)h1s << 16),
                           __ATOMIC_RELAXED, __HIP_MEMORY_SCOPE_AGENT);
        __hip_atomic_store(lp0 + p32, (unsigned int)l0s | ((unsigned int)l1s << 16),
                           __ATOMIC_RELAXED, __HIP_MEMORY_SCOPE_AGENT);
    }

    const int b_el = t >> 2, up = t & 3;           // cell pair (b_el, up*2..+1)
    const int jb = wg * 8 + up * 2;
    float cs0 = c0[b_el * 1024 + jb];
    float cs1 = c0[b_el * 1024 + jb + 1];

    gbar(flags, wg, t, 1u);

    const int arow = (w << 4) + lc;
    const unsigned int* Gu = (const unsigned int*)G;
    for (int step = 0; step < 512; ++step) {
        const unsigned long long* hH =
            (const unsigned long long*)((step & 1) ? hp1 : hp0);
        const unsigned long long* hL =
            (const unsigned long long*)((step & 1) ? lp1 : lp0);
        unsigned int* nH = (step & 1) ? hp0 : hp1;
        unsigned int* nL = (step & 1) ? lp0 : lp1;

        // G prefetch: 4 x bf16-pair (4B) loads; hides under MFMA loop
        size_t gb32 = (size_t)(step * 64 + b_el) * 2048 + wg * 4 + up;
        unsigned int g0 = Gu[gb32];
        unsigned int g1 = Gu[gb32 + 512];
        unsigned int g2 = Gu[gb32 + 1024];
        unsigned int g3 = Gu[gb32 + 1536];

        f32x4 acc[2][3] = {};
#pragma unroll 4
        for (int kb = 0; kb < 32; ++kb) {
            int a64 = ((kb * 4 + lq) * 64 + arow) * 2;
            bf16x8 ah = ld_h16(hH + a64);
            bf16x8 al = ld_h16(hL + a64);
#pragma unroll
            for (int ct = 0; ct < 2; ++ct) {
                int bpos = ct * 16384 + (kb * 64 + l) * 8;
                bf16x8 bh = *(const bf16x8*)&WhHiS[bpos];
                bf16x8 bl = *(const bf16x8*)&WhLoS[bpos];
                acc[ct][0] = __builtin_amdgcn_mfma_f32_16x16x32_bf16(ah, bh, acc[ct][0], 0, 0, 0);
                acc[ct][1] = __builtin_amdgcn_mfma_f32_16x16x32_bf16(al, bh, acc[ct][1], 0, 0, 0);
                acc[ct][2] = __builtin_amdgcn_mfma_f32_16x16x32_bf16(ah, bl, acc[ct][2], 0, 0, 0);
            }
        }

        // z tile -> LDS (row = batch, col = gate*8+unit), stride 33
#pragma unroll
        for (int ct = 0; ct < 2; ++ct)
#pragma unroll
            for (int r = 0; r < 4; ++r)
                zS[(w * 16 + lq * 4 + r) * 33 + ct * 16 + lc] =
                    acc[ct][0][r] + acc[ct][1][r] + acc[ct][2][r];
        __syncthreads();

        const float* zrow = zS + b_el * 33;
        float zi0 = bf2f((unsigned short)(g0 & 0xffff)) + zrow[up * 2];
        float zf0 = bf2f((unsigned short)(g1 & 0xffff)) + zrow[8 + up * 2];
        float zg0 = bf2f((unsigned short)(g2 & 0xffff)) + zrow[16 + up * 2];
        float zo0 = bf2f((unsigned short)(g3 & 0xffff)) + zrow[24 + up * 2];
        float zi1 = bf2f((unsigned short)(g0 >> 16)) + zrow[up * 2 + 1];
        float zf1 = bf2f((unsigned short)(g1 >> 16)) + zrow[8 + up * 2 + 1];
        float zg1 = bf2f((unsigned short)(g2 >> 16)) + zrow[16 + up * 2 + 1];
        float zo1 = bf2f((unsigned short)(g3 >> 16)) + zrow[24 + up * 2 + 1];

        float i0g = 1.f / (1.f + __expf(-zi0));
        float f0g = 1.f / (1.f + __expf(-zf0));
        float g0g = tanhf(zg0);
        float o0g = 1.f / (1.f + __expf(-zo0));
        cs0 = f0g * cs0 + i0g * g0g;
        float nh0 = o0g * tanhf(cs0);

        float i1g = 1.f / (1.f + __expf(-zi1));
        float f1g = 1.f / (1.f + __expf(-zf1));
        float g1g = tanhf(zg1);
        float o1g = 1.f / (1.f + __expf(-zo1));
        cs1 = f1g * cs1 + i1g * g1g;
        float nh1 = o1g * tanhf(cs1);

        float2 ov; ov.x = nh0; ov.y = nh1;
        *(float2*)(out + (size_t)step * 65536 + b_el * 1024 + jb) = ov;

        // publish: p32 = wg*256 + t  (fully coalesced), hi/lo packed pairs
        unsigned short h0s = f2bf(nh0), h1s = f2bf(nh1);
        unsigned short l0s = f2bf(nh0 - bf2f(h0s)), l1s = f2bf(nh1 - bf2f(h1s));
        int p32 = (wg * 64 + b_el) * 4 + up;
        __hip_atomic_store(nH + p32, (unsigned int)h0s | ((unsigned int)h1s << 16),
                           __ATOMIC_RELAXED, __HIP_MEMORY_SCOPE_AGENT);
        __hip_atomic_store(nL + p32, (unsigned int)l0s | ((unsigned int)l1s << 16),
                           __ATOMIC_RELAXED, __HIP_MEMORY_SCOPE_AGENT);

        gbar(flags, wg, t, (unsigned int)(step + 2));
    }
}

// ---------------------------------------------------------------------------
extern "C" void kernel_launch(void* const* d_in, const int* in_sizes, int n_in,
                              void* d_out, int out_size, void* d_ws, size_t ws_size,
                              hipStream_t stream)
{
    const float* x  = (const float*)d_in[0];
    const float* h0 = (const float*)d_in[1];
    const float* c0 = (const float*)d_in[2];
    const float* Wi = (const float*)d_in[3];
    const float* Wh = (const float*)d_in[4];
    const float* bb = (const float*)d_in[5];
    float* out = (float*)d_out;

    // ws layout: 4 hpack (128KB each) | flags 16KB | WiHi 8MB | WiLo 8MB | G 268MB
    unsigned int* hp0 = (unsigned int*)d_ws;
    unsigned int* lp0 = hp0 + 32768;
    unsigned int* hp1 = lp0 + 32768;
    unsigned int* lp1 = hp1 + 32768;
    unsigned int* flags = lp1 + 32768;
    unsigned short* WiHi = (unsigned short*)(flags + 4096);
    unsigned short* WiLo = WiHi + 4194304;
    __hip_bfloat16* G = (__hip_bfloat16*)(WiLo + 4194304);

    hipMemsetAsync(flags, 0, 4096 * sizeof(unsigned int), stream);
    wi_pack<<<dim3(1024), dim3(256), 0, stream>>>(Wi, WiHi, WiLo);
    xwi_gemm_mfma<<<dim3(8192), dim3(256), 0, stream>>>(x, WiHi, WiLo, bb, G);

    void* args[] = {(void*)&G, (void*)&Wh, (void*)&h0, (void*)&c0, (void*)&out,
                    (void*)&hp0, (void*)&lp0, (void*)&hp1, (void*)&lp1,
                    (void*)&flags};
    hipLaunchCooperativeKernel(reinterpret_cast<void*>(&lstm_scan_mfma),
                               dim3(128), dim3(256), args, 0, stream);
}

// Round 5
// 4646.425 us; speedup vs baseline: 10.0861x; 1.6398x over previous
//
#include <hip/hip_runtime.h>
#include <hip/hip_bf16.h>

// T=512, B=64, D=1024, H=1024, 4H=4096
// Pass 0: pack Wi -> split-bf16 (hi/lo) in MFMA B-fragment order (ws, 16MB)
// Pass 1: G2 = x @ Wi + b via split-bf16 MFMA, stored in SCAN-NATIVE layout:
//         G2[((step*256 + wg)*4 + gate)*256 + b*4 + u]  (bf16)
//         -> per step each scan WG reads one contiguous 2KB panel.
// Pass 2: cooperative scan, 256 WGs x 4 hidden units (round-3 shape),
//         split-bf16 MFMA, flag-array barrier, software-pipelined h loads.

typedef __attribute__((ext_vector_type(8))) short bf16x8;
typedef __attribute__((ext_vector_type(8))) unsigned short ushx8;
typedef __attribute__((ext_vector_type(4))) unsigned short ushx4;
typedef __attribute__((ext_vector_type(4))) float f32x4;
typedef __attribute__((ext_vector_type(2))) unsigned long long u64x2;

static __device__ __forceinline__ unsigned short f2bf(float x) {
    __hip_bfloat16 h = __float2bfloat16(x);
    return __builtin_bit_cast(unsigned short, h);
}
static __device__ __forceinline__ float bf2f(unsigned short u) {
    __hip_bfloat16 h = __builtin_bit_cast(__hip_bfloat16, u);
    return __bfloat162float(h);
}

// coherent (agent-scope, L2-bypassing) 16B load as 2 x u64 relaxed atomics
static __device__ __forceinline__ bf16x8 ld_h16(const unsigned long long* p) {
    unsigned long long a = __hip_atomic_load(p,     __ATOMIC_RELAXED, __HIP_MEMORY_SCOPE_AGENT);
    unsigned long long b = __hip_atomic_load(p + 1, __ATOMIC_RELAXED, __HIP_MEMORY_SCOPE_AGENT);
    u64x2 v; v.x = a; v.y = b;
    return __builtin_bit_cast(bf16x8, v);
}

static __device__ __forceinline__ void gl_lds16(const void* g, void* l) {
    __builtin_amdgcn_global_load_lds(
        (const __attribute__((address_space(1))) unsigned int*)g,
        (__attribute__((address_space(3))) unsigned int*)l, 16, 0, 0);
}

static __device__ __forceinline__ float sigm_fast(float x) {
    return 1.f / (1.f + __expf(-x));            // e^-x=inf -> 0 ; ok
}
static __device__ __forceinline__ float tanh_fast(float x) {
    float e = __expf(2.f * x);                  // inf -> 1 ; 0 -> -1 ; no NaN
    return 1.f - 2.f / (e + 1.f);
}

// ---------------------------------------------------------------------------
// Pass 0: pack Wi[1024][4096] f32 -> WiHi/WiLo bf16 in B-fragment order.
// Slab (tn, kb) of 4096 shorts: idx = kq*1024 + c*8 + (k&7).
// ---------------------------------------------------------------------------
__global__ __launch_bounds__(256)
void wi_pack(const float* __restrict__ Wi, unsigned short* __restrict__ WiHi,
             unsigned short* __restrict__ WiLo)
{
    const int bid = blockIdx.x;            // 1024 = tn(32) x kb(32)
    const int tn = bid >> 5, kb = bid & 31;
    const int t = threadIdx.x;
    const int c = t & 127, ko = t >> 7;
    const float* src = Wi + (size_t)(kb * 32 + ko * 16) * 4096 + tn * 128 + c;
    const size_t dbase = ((size_t)(tn * 32 + kb)) * 4096 + c * 8;
#pragma unroll
    for (int o = 0; o < 2; ++o) {
        ushx8 hv, lv;
#pragma unroll
        for (int q = 0; q < 8; ++q) {
            float v = src[(size_t)(o * 8 + q) * 4096];
            unsigned short h = f2bf(v);
            hv[q] = h; lv[q] = f2bf(v - bf2f(h));
        }
        int kq = ko * 2 + o;
        *(ushx8*)(WiHi + dbase + kq * 1024) = hv;
        *(ushx8*)(WiLo + dbase + kq * 1024) = lv;
    }
}

// ---------------------------------------------------------------------------
// Pass 1: G2 = x @ Wi + bias, split-bf16 MFMA, 128x128 tile, BK=32, 4 waves.
// acc quad (r=0..3) = 4 consecutive cols = u=0..3 of one (gate, wg) -> 8B store
// into the scan-native layout.
// ---------------------------------------------------------------------------
__global__ __launch_bounds__(256)
void xwi_gemm_mfma(const float* __restrict__ x,
                   const unsigned short* __restrict__ WiHi,
                   const unsigned short* __restrict__ WiLo,
                   const float* __restrict__ bias,
                   unsigned short* __restrict__ G2)
{
    __shared__ __align__(16) unsigned short AHi[4096], ALo[4096];
    __shared__ __align__(16) unsigned short BHi[4096], BLo[4096];
    const int bid = blockIdx.x;
    const int bm = bid >> 5, bn = bid & 31;
    const int m0 = bm << 7, n0 = bn << 7;
    const int t = threadIdx.x;
    const int w = t >> 6, l = t & 63, lq = l >> 4, lc = l & 15;
    const int wm = w >> 1, wn = w & 1;

    f32x4 acc[4][4] = {};
    const int row = t >> 1, kh = t & 1;
    const float* xrow = x + (size_t)(m0 + row) * 1024 + kh * 16;
    const unsigned short* bHsl = WiHi + (size_t)(bn * 32) * 4096;
    const unsigned short* bLsl = WiLo + (size_t)(bn * 32) * 4096;

    for (int kb = 0; kb < 32; ++kb) {
        float4 f0 = *(const float4*)(xrow + kb * 32 + 0);
        float4 f1 = *(const float4*)(xrow + kb * 32 + 4);
        float4 f2 = *(const float4*)(xrow + kb * 32 + 8);
        float4 f3 = *(const float4*)(xrow + kb * 32 + 12);
        float fs[16] = {f0.x, f0.y, f0.z, f0.w, f1.x, f1.y, f1.z, f1.w,
                        f2.x, f2.y, f2.z, f2.w, f3.x, f3.y, f3.z, f3.w};
#pragma unroll
        for (int o = 0; o < 2; ++o) {
            ushx8 hv, lv;
#pragma unroll
            for (int q = 0; q < 8; ++q) {
                float v = fs[o * 8 + q];
                unsigned short h = f2bf(v);
                hv[q] = h; lv[q] = f2bf(v - bf2f(h));
            }
            int kq = kh * 2 + o;
            *(ushx8*)&AHi[kq * 1024 + row * 8] = hv;
            *(ushx8*)&ALo[kq * 1024 + row * 8] = lv;
        }
        {
            const unsigned short* sH = bHsl + (size_t)kb * 4096;
            const unsigned short* sL = bLsl + (size_t)kb * 4096;
            gl_lds16(sH + (size_t)(w * 128 + l) * 8,      &BHi[(w * 128) * 8]);
            gl_lds16(sH + (size_t)(w * 128 + 64 + l) * 8, &BHi[(w * 128 + 64) * 8]);
            gl_lds16(sL + (size_t)(w * 128 + l) * 8,      &BLo[(w * 128) * 8]);
            gl_lds16(sL + (size_t)(w * 128 + 64 + l) * 8, &BLo[(w * 128 + 64) * 8]);
        }
        __syncthreads();

        bf16x8 xh[4], xl[4], wh_[4], wl_[4];
#pragma unroll
        for (int a = 0; a < 4; ++a) {
            int off = lq * 1024 + (wm * 64 + a * 16 + lc) * 8;
            xh[a] = *(const bf16x8*)&AHi[off];
            xl[a] = *(const bf16x8*)&ALo[off];
        }
#pragma unroll
        for (int b = 0; b < 4; ++b) {
            int off = lq * 1024 + (wn * 64 + b * 16 + lc) * 8;
            wh_[b] = *(const bf16x8*)&BHi[off];
            wl_[b] = *(const bf16x8*)&BLo[off];
        }
#pragma unroll
        for (int a = 0; a < 4; ++a)
#pragma unroll
            for (int b = 0; b < 4; ++b) {
                acc[a][b] = __builtin_amdgcn_mfma_f32_16x16x32_bf16(wh_[b], xh[a], acc[a][b], 0, 0, 0);
                acc[a][b] = __builtin_amdgcn_mfma_f32_16x16x32_bf16(wl_[b], xh[a], acc[a][b], 0, 0, 0);
                acc[a][b] = __builtin_amdgcn_mfma_f32_16x16x32_bf16(wh_[b], xl[a], acc[a][b], 0, 0, 0);
            }
        __syncthreads();
    }

    // epilogue: + bias, store into scan-native layout (8B per quad)
    float bv[4][4];
#pragma unroll
    for (int b = 0; b < 4; ++b)
#pragma unroll
        for (int r = 0; r < 4; ++r)
            bv[b][r] = bias[n0 + wn * 64 + b * 16 + lq * 4 + r];
#pragma unroll
    for (int a = 0; a < 4; ++a) {
        int m = m0 + wm * 64 + a * 16 + lc;
        int step = m >> 6, b_el = m & 63;
#pragma unroll
        for (int b = 0; b < 4; ++b) {
            int j_abs = n0 + wn * 64 + b * 16 + lq * 4;
            int gate = j_abs >> 10;
            int wg_t = (j_abs & 1023) >> 2;
            ushx4 sv;
#pragma unroll
            for (int r = 0; r < 4; ++r) sv[r] = f2bf(acc[a][b][r] + bv[b][r]);
            *(ushx4*)(G2 + (((size_t)(step * 256 + wg_t) * 4 + gate) * 256 + b_el * 4)) = sv;
        }
    }
}

// ---------------------------------------------------------------------------
// Pass 2: cooperative MFMA scan. 256 WGs x 256 threads (4 waves), 4 units/WG.
// Wh slice (16 z-cols, hi/lo split) in LDS; h broadcast via ws in A-fragment
// order (agent-scope atomics); flag-array barrier; K-loop software-pipelined
// in 4 groups of 8 (double-buffered VGPR arrays, static indices).
// ---------------------------------------------------------------------------
__global__ __launch_bounds__(256, 1)
void lstm_scan_mfma(const unsigned short* __restrict__ G2,
                    const float* __restrict__ Wh,
                    const float* __restrict__ h0, const float* __restrict__ c0,
                    float* __restrict__ out,
                    unsigned int* __restrict__ hp0, unsigned int* __restrict__ lp0,
                    unsigned int* __restrict__ hp1, unsigned int* __restrict__ lp1,
                    unsigned int* __restrict__ flags)
{
    __shared__ __align__(16) unsigned short WhHiS[16384];  // 32 KB
    __shared__ __align__(16) unsigned short WhLoS[16384];  // 32 KB
    __shared__ float zS[64 * 20];

    const int t  = threadIdx.x;
    const int wg = blockIdx.x;           // 0..255
    const int w  = t >> 6;
    const int l  = t & 63;
    const int lq = l >> 4, lc = l & 15;

    // Wh slice -> LDS (once): 16 z-cols, hi/lo split, B-fragment order
    for (int idx = t; idx < 16384; idx += 256) {
        int k = idx >> 4, c = idx & 15;
        int gcol = (c >> 2) * 1024 + wg * 4 + (c & 3);
        float wv = Wh[(size_t)k * 4096 + gcol];
        unsigned short hi = f2bf(wv);
        unsigned short lo = f2bf(wv - bf2f(hi));
        int pos = (((k >> 5) * 64) + (((k >> 3) & 3) * 16 + c)) * 8 + (k & 7);
        WhHiS[pos] = hi; WhLoS[pos] = lo;
    }

    // init hpack buffer 0 from h0: one k-pair per thread (32768 pairs)
    {
        int idx = wg * 256 + t;
        if (idx < 32768) {
            int b = idx >> 9, k = (idx & 511) * 2;
            float v0 = h0[b * 1024 + k], v1 = h0[b * 1024 + k + 1];
            unsigned short h0s = f2bf(v0), h1s = f2bf(v1);
            unsigned short l0s = f2bf(v0 - bf2f(h0s)), l1s = f2bf(v1 - bf2f(h1s));
            int p32 = ((k >> 3) * 64 + b) * 4 + ((k & 7) >> 1);
            __hip_atomic_store(hp0 + p32, (unsigned int)h0s | ((unsigned int)h1s << 16),
                               __ATOMIC_RELAXED, __HIP_MEMORY_SCOPE_AGENT);
            __hip_atomic_store(lp0 + p32, (unsigned int)l0s | ((unsigned int)l1s << 16),
                               __ATOMIC_RELAXED, __HIP_MEMORY_SCOPE_AGENT);
        }
    }

    const int b_el = t >> 2, u_el = t & 3;
    const int j = wg * 4 + u_el;
    float c_state = c0[b_el * 1024 + j];

    // ---- barrier helper inlined (arrive / poll split around deferred work)
    // initial barrier
    {
        asm volatile("s_waitcnt vmcnt(0)" ::: "memory");
        __syncthreads();
        if (t == 0)
            __hip_atomic_store(&flags[wg * 32], 1u, __ATOMIC_RELAXED,
                               __HIP_MEMORY_SCOPE_AGENT);
        while (__hip_atomic_load(&flags[t * 32], __ATOMIC_RELAXED,
                                 __HIP_MEMORY_SCOPE_AGENT) < 1u) {}
        __syncthreads();
        asm volatile("" ::: "memory");
    }

    const int arow = (w << 4) + lc;
    for (int step = 0; step < 512; ++step) {
        const unsigned long long* hH =
            (const unsigned long long*)((step & 1) ? hp1 : hp0);
        const unsigned long long* hL =
            (const unsigned long long*)((step & 1) ? lp1 : lp0);
        unsigned int* nH = (step & 1) ? hp0 : hp1;
        unsigned int* nL = (step & 1) ? lp0 : lp1;

        // G prefetch: contiguous 2KB/WG panel, 4 x 2B per thread (dense)
        size_t pb = ((size_t)(step * 256 + wg) * 4) * 256 + t;
        unsigned short gvi = G2[pb];
        unsigned short gvf = G2[pb + 256];
        unsigned short gvg = G2[pb + 512];
        unsigned short gvo = G2[pb + 768];

        f32x4 acc0 = {0.f, 0.f, 0.f, 0.f};
        f32x4 acc1 = {0.f, 0.f, 0.f, 0.f};
        f32x4 acc2 = {0.f, 0.f, 0.f, 0.f};

        // software-pipelined K loop: 4 groups of 8 kb, double-buffered regs
        bf16x8 ah[2][8], al[2][8];
#pragma unroll
        for (int i = 0; i < 8; ++i) {
            int a64 = ((i * 4 + lq) * 64 + arow) * 2;
            ah[0][i] = ld_h16(hH + a64);
            al[0][i] = ld_h16(hL + a64);
        }
#pragma unroll
        for (int g4 = 0; g4 < 4; ++g4) {
            if (g4 < 3) {
#pragma unroll
                for (int i = 0; i < 8; ++i) {
                    int kb = (g4 + 1) * 8 + i;
                    int a64 = ((kb * 4 + lq) * 64 + arow) * 2;
                    ah[(g4 + 1) & 1][i] = ld_h16(hH + a64);
                    al[(g4 + 1) & 1][i] = ld_h16(hL + a64);
                }
            }
#pragma unroll
            for (int i = 0; i < 8; ++i) {
                int kb = g4 * 8 + i;
                int bpos = (kb * 64 + l) * 8;
                bf16x8 bh = *(const bf16x8*)&WhHiS[bpos];
                bf16x8 bl = *(const bf16x8*)&WhLoS[bpos];
                bf16x8 a_h = ah[g4 & 1][i];
                bf16x8 a_l = al[g4 & 1][i];
                acc0 = __builtin_amdgcn_mfma_f32_16x16x32_bf16(a_h, bh, acc0, 0, 0, 0);
                acc1 = __builtin_amdgcn_mfma_f32_16x16x32_bf16(a_l, bh, acc1, 0, 0, 0);
                acc2 = __builtin_amdgcn_mfma_f32_16x16x32_bf16(a_h, bl, acc2, 0, 0, 0);
            }
        }

        // z tile -> LDS transpose (stride 20: <=2-way banks, free)
#pragma unroll
        for (int r = 0; r < 4; ++r)
            zS[(w * 16 + lq * 4 + r) * 20 + lc] = acc0[r] + acc1[r] + acc2[r];
        __syncthreads();

        float zi = bf2f(gvi) + zS[b_el * 20 + u_el];
        float zf = bf2f(gvf) + zS[b_el * 20 + 4 + u_el];
        float zg = bf2f(gvg) + zS[b_el * 20 + 8 + u_el];
        float zo = bf2f(gvo) + zS[b_el * 20 + 12 + u_el];

        float ig = sigm_fast(zi);
        float fg = sigm_fast(zf);
        float gg = tanh_fast(zg);
        float og = sigm_fast(zo);

        c_state = fg * c_state + ig * gg;
        float nh = og * tanh_fast(c_state);

        // publish h (agent-scope, packed pairs via shfl)
        unsigned int hiw = f2bf(nh);
        unsigned int low = f2bf(nh - bf2f((unsigned short)hiw));
        unsigned int hi_o = (unsigned int)__shfl_xor((int)hiw, 1);
        unsigned int lo_o = (unsigned int)__shfl_xor((int)low, 1);
        if ((t & 1) == 0) {
            int p32 = ((j >> 3) * 64 + b_el) * 4 + ((j & 7) >> 1);
            __hip_atomic_store(nH + p32, (hiw & 0xffffu) | (hi_o << 16),
                               __ATOMIC_RELAXED, __HIP_MEMORY_SCOPE_AGENT);
            __hip_atomic_store(nL + p32, (low & 0xffffu) | (lo_o << 16),
                               __ATOMIC_RELAXED, __HIP_MEMORY_SCOPE_AGENT);
        }

        // barrier arrive (h drained), then deferred out store, then poll
        asm volatile("s_waitcnt vmcnt(0)" ::: "memory");
        __syncthreads();
        unsigned int target = (unsigned int)(step + 2);
        if (t == 0)
            __hip_atomic_store(&flags[wg * 32], target, __ATOMIC_RELAXED,
                               __HIP_MEMORY_SCOPE_AGENT);
        out[(size_t)step * 65536 + b_el * 1024 + j] = nh;   // drains next step
        while (__hip_atomic_load(&flags[t * 32], __ATOMIC_RELAXED,
                                 __HIP_MEMORY_SCOPE_AGENT) < target) {}
        __syncthreads();
        asm volatile("" ::: "memory");
    }
}

// ---------------------------------------------------------------------------
extern "C" void kernel_launch(void* const* d_in, const int* in_sizes, int n_in,
                              void* d_out, int out_size, void* d_ws, size_t ws_size,
                              hipStream_t stream)
{
    const float* x  = (const float*)d_in[0];
    const float* h0 = (const float*)d_in[1];
    const float* c0 = (const float*)d_in[2];
    const float* Wi = (const float*)d_in[3];
    const float* Wh = (const float*)d_in[4];
    const float* bb = (const float*)d_in[5];
    float* out = (float*)d_out;

    // ws layout: 4 hpack (128KB each) | flags 16KB | WiHi 8MB | WiLo 8MB | G2 268MB
    unsigned int* hp0 = (unsigned int*)d_ws;
    unsigned int* lp0 = hp0 + 32768;
    unsigned int* hp1 = lp0 + 32768;
    unsigned int* lp1 = hp1 + 32768;
    unsigned int* flags = lp1 + 32768;
    unsigned short* WiHi = (unsigned short*)(flags + 4096);
    unsigned short* WiLo = WiHi + 4194304;
    unsigned short* G2 = WiLo + 4194304;

    hipMemsetAsync(flags, 0, 4096 * sizeof(unsigned int), stream);
    wi_pack<<<dim3(1024), dim3(256), 0, stream>>>(Wi, WiHi, WiLo);
    xwi_gemm_mfma<<<dim3(8192), dim3(256), 0, stream>>>(x, WiHi, WiLo, bb, G2);

    void* args[] = {(void*)&G2, (void*)&Wh, (void*)&h0, (void*)&c0, (void*)&out,
                    (void*)&hp0, (void*)&lp0, (void*)&hp1, (void*)&lp1,
                    (void*)&flags};
    hipLaunchCooperativeKernel(reinterpret_cast<void*>(&lstm_scan_mfma),
                               dim3(256), dim3(256), args, 0, stream);
}